// Round 1
// baseline (393.585 us; speedup 1.0000x reference)
//
#include <hip/hip_runtime.h>
#include <math.h>

#define LEAKY 0.2f
__device__ __forceinline__ float lrelu(float x){ return x >= 0.0f ? x : LEAKY*x; }

#define BD   128
#define NPTS 4096
#define MPTS 1024

// ---------------------------------------------------------------------------
// Local encoder: 1024 pts x (3->64->256), max over points.
// grid 512 (B*4 chunks of 256 points), block 256. Thread-per-point, h[64] in
// VGPRs, w2 accessed with wave-uniform index -> scalar loads (FMA-bound).
// ---------------------------------------------------------------------------
__global__ __launch_bounds__(256) void k_local(
    const float* __restrict__ pc,   // [B,1024,3]
    const float* __restrict__ w1,   // [3,64]
    const float* __restrict__ b1,   // [64]
    const float* __restrict__ w2,   // [64,256]
    const float* __restrict__ b2,   // [256]
    float* __restrict__ part)       // [512,256]
{
    int blk = blockIdx.x;
    int b = blk >> 2, chunk = blk & 3;
    int t = threadIdx.x;
    int m = chunk*256 + t;
    const float* p = pc + ((size_t)b*MPTS + m)*3;
    float x = p[0], y = p[1], z = p[2];
    float h[64];
#pragma unroll
    for (int k = 0; k < 64; ++k)
        h[k] = lrelu(fmaf(x, w1[k], fmaf(y, w1[64+k], fmaf(z, w1[128+k], b1[k]))));

    __shared__ float wmax[4][256];
    int wv = t >> 6;
    for (int c0 = 0; c0 < 256; c0 += 4) {
        float a0 = b2[c0], a1 = b2[c0+1], a2 = b2[c0+2], a3 = b2[c0+3];
#pragma unroll
        for (int k = 0; k < 64; ++k) {
            const float* wr = w2 + k*256 + c0;   // uniform address -> s_load
            float hv = h[k];
            a0 = fmaf(hv, wr[0], a0);
            a1 = fmaf(hv, wr[1], a1);
            a2 = fmaf(hv, wr[2], a2);
            a3 = fmaf(hv, wr[3], a3);
        }
        a0 = lrelu(a0); a1 = lrelu(a1); a2 = lrelu(a2); a3 = lrelu(a3);
#pragma unroll
        for (int off = 32; off; off >>= 1) {
            a0 = fmaxf(a0, __shfl_xor(a0, off, 64));
            a1 = fmaxf(a1, __shfl_xor(a1, off, 64));
            a2 = fmaxf(a2, __shfl_xor(a2, off, 64));
            a3 = fmaxf(a3, __shfl_xor(a3, off, 64));
        }
        if ((t & 63) == 0) {
            wmax[wv][c0]   = a0; wmax[wv][c0+1] = a1;
            wmax[wv][c0+2] = a2; wmax[wv][c0+3] = a3;
        }
    }
    __syncthreads();
    float v = fmaxf(fmaxf(wmax[0][t], wmax[1][t]), fmaxf(wmax[2][t], wmax[3][t]));
    part[blk*256 + t] = v;
}

__global__ __launch_bounds__(256) void k_localfin(const float* __restrict__ part,
                                                  float* __restrict__ feat)
{
    int b = blockIdx.x, t = threadIdx.x;
    float v =          part[(b*4+0)*256+t];
    v = fmaxf(v, part[(b*4+1)*256+t]);
    v = fmaxf(v, part[(b*4+2)*256+t]);
    v = fmaxf(v, part[(b*4+3)*256+t]);
    feat[(size_t)b*4608 + 2048 + t] = v;
}

// ---------------------------------------------------------------------------
// KNN top-16 + selected-point PointNet features + attention + pos-embed.
// One block per batch, 256 threads. Writes feat[2304:2560].
// ---------------------------------------------------------------------------
__global__ __launch_bounds__(256) void k_knn_attn(
    const float* __restrict__ gpc,     // [B,4096,3]
    const float* __restrict__ query,   // [B,1,3]
    const float* __restrict__ ge_w1, const float* __restrict__ ge_b1,
    const float* __restrict__ ge_w2, const float* __restrict__ ge_b2,
    const float* __restrict__ apw, const float* __restrict__ apb,
    const float* __restrict__ asw, const float* __restrict__ asb,
    const float* __restrict__ pos_w, const float* __restrict__ pos_b,
    const float* __restrict__ bn_g, const float* __restrict__ bn_b,
    float* __restrict__ feat)
{
    int b = blockIdx.x, t = threadIdx.x;
    __shared__ float sdw[4]; __shared__ int siw[4];
    __shared__ int   knn_idx[16];
    __shared__ float knn_pos[16][3];
    __shared__ float hlds[64];
    __shared__ float knn_feat[16][128];
    __shared__ float hq[16][128];
    __shared__ float spart[2][16][128];

    const float* pb = gpc + (size_t)b*NPTS*3;
    float qx = query[b*3+0], qy = query[b*3+1], qz = query[b*3+2];
    float sq = qx*qx + qy*qy + qz*qz;

    float d2[16];
    int used = 0;
#pragma unroll
    for (int j = 0; j < 16; ++j) {
        int n = t + 256*j;
        float px = pb[n*3+0], py = pb[n*3+1], pz = pb[n*3+2];
        float sp = px*px + py*py + pz*pz;
        d2[j] = sq + sp - 2.0f*(qx*px + qy*py + qz*pz);  // same formula as ref
    }
    for (int r = 0; r < 16; ++r) {
        float bd = INFINITY; int bi = 0x7fffffff;
#pragma unroll
        for (int j = 0; j < 16; ++j) {
            float d = (used & (1<<j)) ? INFINITY : d2[j];
            int n = t + 256*j;
            if (d < bd || (d == bd && n < bi)) { bd = d; bi = n; }
        }
#pragma unroll
        for (int off = 32; off; off >>= 1) {
            float od = __shfl_xor(bd, off, 64);
            int   oi = __shfl_xor(bi, off, 64);
            if (od < bd || (od == bd && oi < bi)) { bd = od; bi = oi; }
        }
        if ((t & 63) == 0) { sdw[t>>6] = bd; siw[t>>6] = bi; }
        __syncthreads();
        if (t == 0) {
            float fd = sdw[0]; int fi = siw[0];
#pragma unroll
            for (int w = 1; w < 4; ++w)
                if (sdw[w] < fd || (sdw[w] == fd && siw[w] < fi)) { fd = sdw[w]; fi = siw[w]; }
            knn_idx[r] = fi;
            knn_pos[r][0] = qx - pb[fi*3+0];
            knn_pos[r][1] = qy - pb[fi*3+1];
            knn_pos[r][2] = qz - pb[fi*3+2];
        }
        __syncthreads();
        int win = knn_idx[r];
        if ((win & 255) == t) used |= 1 << (win >> 8);
    }
    // point features for the 16 selected neighbors (3->64->128)
    for (int r = 0; r < 16; ++r) {
        int n = knn_idx[r];
        if (t < 64) {
            float px = pb[n*3+0], py = pb[n*3+1], pz = pb[n*3+2];
            hlds[t] = lrelu(fmaf(px, ge_w1[t], fmaf(py, ge_w1[64+t], fmaf(pz, ge_w1[128+t], ge_b1[t]))));
        }
        __syncthreads();
        if (t < 128) {
            float acc = ge_b2[t];
#pragma unroll
            for (int k = 0; k < 64; ++k) acc = fmaf(hlds[k], ge_w2[k*128 + t], acc);
            knn_feat[r][t] = lrelu(acc);
        }
        __syncthreads();
    }
    // attention
    int c = t & 127, half = t >> 7;
    if (t < 128) {
        for (int r = 0; r < 16; ++r) {
            float pe = fmaf(knn_pos[r][0], apw[c],
                       fmaf(knn_pos[r][1], apw[128+c],
                       fmaf(knn_pos[r][2], apw[256+c], apb[c])));
            hq[r][c] = knn_feat[r][c] + pe;
        }
    }
    __syncthreads();
    float s[16];
#pragma unroll
    for (int r = 0; r < 16; ++r) s[r] = 0.0f;
    for (int j = half*64; j < half*64 + 64; ++j) {
        float wvv = asw[j*128 + c];
#pragma unroll
        for (int r = 0; r < 16; ++r) s[r] = fmaf(hq[r][j], wvv, s[r]);
    }
#pragma unroll
    for (int r = 0; r < 16; ++r) spart[half][r][c] = s[r];
    __syncthreads();
    if (t < 128) {
        float mx = -INFINITY;
#pragma unroll
        for (int r = 0; r < 16; ++r) {
            s[r] = spart[0][r][c] + spart[1][r][c] + asb[c];
            mx = fmaxf(mx, s[r]);
        }
        float sum = 0.0f;
#pragma unroll
        for (int r = 0; r < 16; ++r) { s[r] = expf(s[r] - mx); sum += s[r]; }
        float inv = 1.0f / sum;
        float qf = 0.0f;
#pragma unroll
        for (int r = 0; r < 16; ++r) qf = fmaf(s[r]*inv, hq[r][c], qf);
        feat[(size_t)b*4608 + 2304 + c] = qf;
        // position embedding of query (linear + eval-mode BN affine + lrelu)
        float pv = fmaf(qx, pos_w[c], fmaf(qy, pos_w[128+c], fmaf(qz, pos_w[256+c], pos_b[c])));
        pv = lrelu(fmaf(bn_g[c], pv, bn_b[c]));
        feat[(size_t)b*4608 + 2432 + c] = pv;
    }
}

// ---------------------------------------------------------------------------
// Fused voxel branch: conv3d s2 (1->16) + lrelu + conv3d s2 (16->32) + lrelu.
// grid 256 = 2 branches x 128 batches. SAME padding = (lo 0, hi 1) both convs.
// LDS layouts padded so stride-2 reads are broadcast/conflict-free.
// ---------------------------------------------------------------------------
__global__ __launch_bounds__(256) void k_voxel(
    const float* __restrict__ pcv, const float* __restrict__ vox,
    const float* __restrict__ gw1, const float* __restrict__ gb1,
    const float* __restrict__ gw2, const float* __restrict__ gb2,
    const float* __restrict__ fw1, const float* __restrict__ fb1,
    const float* __restrict__ fw2, const float* __restrict__ fb2,
    float* __restrict__ feat)
{
    int blk = blockIdx.x;
    int branch = blk >> 7, b = blk & 127;
    const float* in = (branch ? vox : pcv) + (size_t)b*4096;
    const float* w1 = branch ? fw1 : gw1;
    const float* b1 = branch ? fb1 : gb1;
    const float* w2 = branch ? fw2 : gw2;
    const float* b2 = branch ? fb2 : gb2;

    __shared__ float s_in[16*16*17];   // [id][ih(17)][iw]
    __shared__ float s_mid[16*576];    // [co][od*72 + oh*9 + ow]
    __shared__ float s_w1[432];

    int t = threadIdx.x;
    for (int i = t; i < 4096; i += 256) {
        int id = i >> 8, ih = (i >> 4) & 15, iw = i & 15;
        s_in[id*272 + ih*17 + iw] = in[i];
    }
    for (int i = t; i < 432; i += 256) s_w1[i] = w1[i];
    __syncthreads();

    { // conv1: co = t&15, spg = t>>4; 32 outputs per thread
        int co = t & 15, spg = t >> 4;
        float wreg[27];
#pragma unroll
        for (int kp = 0; kp < 27; ++kp) wreg[kp] = s_w1[kp*16 + co];
        float bias = b1[co];
        for (int j = 0; j < 32; ++j) {
            int sp = j*16 + spg;
            int od = sp >> 6, oh = (sp >> 3) & 7, ow = sp & 7;
            float acc = bias;
#pragma unroll
            for (int kd = 0; kd < 3; ++kd) {
                int id = 2*od + kd; if (id > 15) continue;
#pragma unroll
                for (int kh = 0; kh < 3; ++kh) {
                    int ih = 2*oh + kh; if (ih > 15) continue;
                    const float* row = s_in + id*272 + ih*17 + 2*ow;
#pragma unroll
                    for (int kw = 0; kw < 3; ++kw) {
                        if (2*ow + kw > 15) continue;
                        acc = fmaf(row[kw], wreg[(kd*3+kh)*3+kw], acc);
                    }
                }
            }
            s_mid[co*576 + od*72 + oh*9 + ow] = lrelu(acc);
        }
    }
    __syncthreads();

    { // conv2: co = t&15 (handles co and co+16), spq = t>>4; od = j (0..3)
        int co = t & 15, spq = t >> 4;
        int oh = (spq >> 2) & 3, ow = spq & 3;
        float acc0[4], acc1[4];
#pragma unroll
        for (int j = 0; j < 4; ++j) { acc0[j] = b2[co]; acc1[j] = b2[co+16]; }
        for (int ci = 0; ci < 16; ++ci) {
            float wa[27], wb[27];
#pragma unroll
            for (int kp = 0; kp < 27; ++kp) {
                wa[kp] = w2[(kp*16 + ci)*32 + co];
                wb[kp] = w2[(kp*16 + ci)*32 + co + 16];
            }
            const float* cbase = s_mid + ci*576;
#pragma unroll
            for (int j = 0; j < 4; ++j) {
#pragma unroll
                for (int kd = 0; kd < 3; ++kd) {
                    int id = 2*j + kd; if (id > 7) continue;
#pragma unroll
                    for (int kh = 0; kh < 3; ++kh) {
                        int ih = 2*oh + kh; if (ih > 7) continue;
                        const float* row = cbase + id*72 + ih*9 + 2*ow;
#pragma unroll
                        for (int kw = 0; kw < 3; ++kw) {
                            if (2*ow + kw > 7) continue;
                            float v = row[kw];
                            int kp = (kd*3+kh)*3+kw;
                            acc0[j] = fmaf(v, wa[kp], acc0[j]);
                            acc1[j] = fmaf(v, wb[kp], acc1[j]);
                        }
                    }
                }
            }
        }
        float* o = feat + (size_t)b*4608 + (branch ? 2560 : 0);
#pragma unroll
        for (int j = 0; j < 4; ++j) {
            int sp = j*16 + spq;
            o[co*64 + sp]      = lrelu(acc0[j]);
            o[(co+16)*64 + sp] = lrelu(acc1[j]);
        }
    }
}

// ---------------------------------------------------------------------------
// Decoder layer 1: [128,4608] @ [4608,512], split i into 32 chunks.
// grid 256 = 8 batch-groups(16) x 32 i-chunks(144). feat rows via s_load.
// ---------------------------------------------------------------------------
__global__ __launch_bounds__(256) void k_dec1(
    const float* __restrict__ feat, const float* __restrict__ w1,
    float* __restrict__ part)       // [32][128][512]
{
    int blk = blockIdx.x;
    int bg = blk >> 5;
    int is = blk & 31;
    int t  = threadIdx.x;
    int i0 = is * 144;
    float acc0[16], acc1[16];
#pragma unroll
    for (int bb = 0; bb < 16; ++bb) { acc0[bb] = 0.f; acc1[bb] = 0.f; }
    const float* fbase = feat + bg*16*4608;
    for (int i = i0; i < i0 + 144; ++i) {
        float wva = w1[(size_t)i*512 + t];
        float wvb = w1[(size_t)i*512 + t + 256];
#pragma unroll
        for (int bb = 0; bb < 16; ++bb) {
            float f = fbase[bb*4608 + i];   // uniform -> s_load
            acc0[bb] = fmaf(f, wva, acc0[bb]);
            acc1[bb] = fmaf(f, wvb, acc1[bb]);
        }
    }
#pragma unroll
    for (int bb = 0; bb < 16; ++bb) {
        part[((size_t)is*128 + bg*16 + bb)*512 + t]       = acc0[bb];
        part[((size_t)is*128 + bg*16 + bb)*512 + t + 256] = acc1[bb];
    }
}

// Decoder: combine partials, bias+lrelu, dot with dec_w2, +b2.
__global__ __launch_bounds__(512) void k_dec2(
    const float* __restrict__ part, const float* __restrict__ b1,
    const float* __restrict__ w2, const float* __restrict__ b2,
    float* __restrict__ out)
{
    int b = blockIdx.x, t = threadIdx.x;
    float acc = b1[t];
    for (int is = 0; is < 32; ++is)
        acc += part[((size_t)is*128 + b)*512 + t];
    float v = lrelu(acc) * w2[t];
#pragma unroll
    for (int off = 32; off; off >>= 1) v += __shfl_xor(v, off, 64);
    __shared__ float red[8];
    if ((t & 63) == 0) red[t >> 6] = v;
    __syncthreads();
    if (t == 0) {
        float s_ = 0.f;
#pragma unroll
        for (int i = 0; i < 8; ++i) s_ += red[i];
        out[b] = s_ + b2[0];
    }
}

extern "C" void kernel_launch(void* const* d_in, const int* in_sizes, int n_in,
                              void* d_out, int out_size, void* d_ws, size_t ws_size,
                              hipStream_t stream)
{
    const float* pc_voxel  = (const float*)d_in[0];
    const float* global_pc = (const float*)d_in[1];
    const float* local_pc  = (const float*)d_in[2];
    const float* query     = (const float*)d_in[3];
    const float* voxel     = (const float*)d_in[4];
    const float* ge_w1 = (const float*)d_in[5];
    const float* ge_b1 = (const float*)d_in[6];
    const float* ge_w2 = (const float*)d_in[7];
    const float* ge_b2 = (const float*)d_in[8];
    // d_in[9], d_in[10] = ge_w3/ge_b3: dead code (global_c unused by decoder)
    const float* le_w1 = (const float*)d_in[11];
    const float* le_b1 = (const float*)d_in[12];
    const float* le_w2 = (const float*)d_in[13];
    const float* le_b2 = (const float*)d_in[14];
    const float* pos_w = (const float*)d_in[15];
    const float* pos_b = (const float*)d_in[16];
    const float* bn_g  = (const float*)d_in[17];
    const float* bn_b  = (const float*)d_in[18];
    const float* apw   = (const float*)d_in[19];
    const float* apb   = (const float*)d_in[20];
    const float* asw   = (const float*)d_in[21];
    const float* asb   = (const float*)d_in[22];
    const float* gw1 = (const float*)d_in[23];
    const float* gb1 = (const float*)d_in[24];
    const float* gw2 = (const float*)d_in[25];
    const float* gb2 = (const float*)d_in[26];
    const float* fw1 = (const float*)d_in[27];
    const float* fb1 = (const float*)d_in[28];
    const float* fw2 = (const float*)d_in[29];
    const float* fb2 = (const float*)d_in[30];
    const float* dw1 = (const float*)d_in[31];
    const float* db1 = (const float*)d_in[32];
    const float* dw2 = (const float*)d_in[33];
    const float* db2 = (const float*)d_in[34];

    float* ws    = (float*)d_ws;
    float* feat  = ws;                       // 128*4608          = 589824
    float* lpart = ws + 589824;              // 512*256           = 131072
    float* dpart = ws + 589824 + 131072;     // 32*128*512        = 2097152
    float* out   = (float*)d_out;

    k_voxel<<<256, 256, 0, stream>>>(pc_voxel, voxel, gw1, gb1, gw2, gb2,
                                     fw1, fb1, fw2, fb2, feat);
    k_local<<<512, 256, 0, stream>>>(local_pc, le_w1, le_b1, le_w2, le_b2, lpart);
    k_localfin<<<128, 256, 0, stream>>>(lpart, feat);
    k_knn_attn<<<128, 256, 0, stream>>>(global_pc, query, ge_w1, ge_b1, ge_w2, ge_b2,
                                        apw, apb, asw, asb, pos_w, pos_b, bn_g, bn_b, feat);
    k_dec1<<<256, 256, 0, stream>>>(feat, dw1, dpart);
    k_dec2<<<128, 512, 0, stream>>>(dpart, db1, dw2, db2, out);
}

// Round 2
// 261.740 us; speedup vs baseline: 1.5037x; 1.5037x over previous
//
#include <hip/hip_runtime.h>
#include <math.h>

#define LEAKY 0.2f
__device__ __forceinline__ float lrelu(float x){ return x >= 0.0f ? x : LEAKY*x; }

// round-to-nearest-even f32 -> bf16 bits
__device__ __forceinline__ unsigned short f2bf(float x){
    union { float f; unsigned u; } v; v.f = x;
    unsigned r = v.u + 0x7FFFu + ((v.u >> 16) & 1u);
    return (unsigned short)(r >> 16);
}
__device__ __forceinline__ unsigned pack2(float a, float b){
    return (unsigned)f2bf(a) | ((unsigned)f2bf(b) << 16);
}

typedef __attribute__((ext_vector_type(8))) short bf16x8;
typedef __attribute__((ext_vector_type(4))) float f32x4;

// ---------------------------------------------------------------------------
// Fused kernel: blocks [0,256) voxel-conv branches, [256,384) local encoder
// (bf16 MFMA), [384,512) KNN+attention. All write feat_bf[128][4608] (bf16).
// smem: 56064 B max (voxel) -> 2 blocks/CU.
// ---------------------------------------------------------------------------
__global__ __launch_bounds__(256) void k_fused(
    // voxel
    const float* __restrict__ pcv, const float* __restrict__ vox,
    const float* __restrict__ gvw1, const float* __restrict__ gvb1,
    const float* __restrict__ gvw2, const float* __restrict__ gvb2,
    const float* __restrict__ fvw1, const float* __restrict__ fvb1,
    const float* __restrict__ fvw2, const float* __restrict__ fvb2,
    // local
    const float* __restrict__ lpc,
    const float* __restrict__ lw1, const float* __restrict__ lb1,
    const float* __restrict__ lw2, const float* __restrict__ lb2,
    // knn / attention
    const float* __restrict__ gpc, const float* __restrict__ query,
    const float* __restrict__ gw1, const float* __restrict__ gb1,
    const float* __restrict__ gw2, const float* __restrict__ gb2,
    const float* __restrict__ apw, const float* __restrict__ apb,
    const float* __restrict__ asw, const float* __restrict__ asb,
    const float* __restrict__ posw, const float* __restrict__ posb,
    const float* __restrict__ bng, const float* __restrict__ bnb,
    unsigned short* __restrict__ featb)
{
    __shared__ __align__(16) unsigned char smem[56064];
    int blk = blockIdx.x;
    int t = threadIdx.x;

    if (blk < 256) {
        // ================= VOXEL BRANCH =================
        int branch = blk >> 7, b = blk & 127;
        const float* in = (branch ? vox : pcv) + (size_t)b*4096;
        const float* w1 = branch ? fvw1 : gvw1;
        const float* b1 = branch ? fvb1 : gvb1;
        const float* w2 = branch ? fvw2 : gvw2;
        const float* b2 = branch ? fvb2 : gvb2;

        float* s_in  = (float*)smem;              // [16][16][17] = 4352 f
        float* s_mid = (float*)(smem + 17408);    // [16][576]    = 9216 f
        float* s_w1  = (float*)(smem + 54272);    // [432]

        for (int i = t; i < 4096; i += 256) {
            int id = i >> 8, ih = (i >> 4) & 15, iw = i & 15;
            s_in[id*272 + ih*17 + iw] = in[i];
        }
        for (int i = t; i < 432; i += 256) s_w1[i] = w1[i];
        __syncthreads();

        { // conv1
            int co = t & 15, spg = t >> 4;
            float wreg[27];
#pragma unroll
            for (int kp = 0; kp < 27; ++kp) wreg[kp] = s_w1[kp*16 + co];
            float bias = b1[co];
            for (int j = 0; j < 32; ++j) {
                int sp = j*16 + spg;
                int od = sp >> 6, oh = (sp >> 3) & 7, ow = sp & 7;
                float acc = bias;
#pragma unroll
                for (int kd = 0; kd < 3; ++kd) {
                    int id = 2*od + kd; if (id > 15) continue;
#pragma unroll
                    for (int kh = 0; kh < 3; ++kh) {
                        int ih = 2*oh + kh; if (ih > 15) continue;
                        const float* row = s_in + id*272 + ih*17 + 2*ow;
#pragma unroll
                        for (int kw = 0; kw < 3; ++kw) {
                            if (2*ow + kw > 15) continue;
                            acc = fmaf(row[kw], wreg[(kd*3+kh)*3+kw], acc);
                        }
                    }
                }
                s_mid[co*576 + od*72 + oh*9 + ow] = lrelu(acc);
            }
        }
        __syncthreads();

        { // conv2
            int co = t & 15, spq = t >> 4;
            int oh = (spq >> 2) & 3, ow = spq & 3;
            float acc0[4], acc1[4];
#pragma unroll
            for (int j = 0; j < 4; ++j) { acc0[j] = b2[co]; acc1[j] = b2[co+16]; }
            for (int ci = 0; ci < 16; ++ci) {
                float wa[27], wb[27];
#pragma unroll
                for (int kp = 0; kp < 27; ++kp) {
                    wa[kp] = w2[(kp*16 + ci)*32 + co];
                    wb[kp] = w2[(kp*16 + ci)*32 + co + 16];
                }
                const float* cbase = s_mid + ci*576;
#pragma unroll
                for (int j = 0; j < 4; ++j) {
#pragma unroll
                    for (int kd = 0; kd < 3; ++kd) {
                        int id = 2*j + kd; if (id > 7) continue;
#pragma unroll
                        for (int kh = 0; kh < 3; ++kh) {
                            int ih = 2*oh + kh; if (ih > 7) continue;
                            const float* row = cbase + id*72 + ih*9 + 2*ow;
#pragma unroll
                            for (int kw = 0; kw < 3; ++kw) {
                                if (2*ow + kw > 7) continue;
                                float v = row[kw];
                                int kp = (kd*3+kh)*3+kw;
                                acc0[j] = fmaf(v, wa[kp], acc0[j]);
                                acc1[j] = fmaf(v, wb[kp], acc1[j]);
                            }
                        }
                    }
                }
            }
            unsigned short* o = featb + (size_t)b*4608 + (branch ? 2560 : 0);
#pragma unroll
            for (int j = 0; j < 4; ++j) {
                int sp = j*16 + spq;
                o[co*64 + sp]      = f2bf(lrelu(acc0[j]));
                o[(co+16)*64 + sp] = f2bf(lrelu(acc1[j]));
            }
        }
    } else if (blk < 384) {
        // ================= LOCAL ENCODER (bf16 MFMA) =================
        int b = blk - 256;
        int w = t >> 6, l = t & 63;
        unsigned char* lds = smem;   // B-stage 32KB, then reused for h 32KB

        // stage B = lw2^T [c][k] bf16, XOR-swizzled 16B slots (thread t = col c)
#pragma unroll
        for (int q = 0; q < 8; ++q) {
            float f0 = lw2[(q*8+0)*256 + t], f1 = lw2[(q*8+1)*256 + t];
            float f2 = lw2[(q*8+2)*256 + t], f3 = lw2[(q*8+3)*256 + t];
            float f4 = lw2[(q*8+4)*256 + t], f5 = lw2[(q*8+5)*256 + t];
            float f6 = lw2[(q*8+6)*256 + t], f7 = lw2[(q*8+7)*256 + t];
            uint4 u = make_uint4(pack2(f0,f1), pack2(f2,f3), pack2(f4,f5), pack2(f6,f7));
            *(uint4*)(lds + t*128 + ((q ^ (t & 7)) * 16)) = u;
        }
        __syncthreads();

        // each wave caches B-fragments for its 64 channels (4 col-tiles x 2 k-steps)
        bf16x8 Bf[4][2];
#pragma unroll
        for (int c4 = 0; c4 < 4; ++c4) {
#pragma unroll
            for (int ks = 0; ks < 2; ++ks) {
                int c = w*64 + c4*16 + (l & 15);
                int chunk = ks*4 + (l >> 4);
                Bf[c4][ks] = *(const bf16x8*)(lds + c*128 + ((chunk ^ (c & 7)) * 16));
            }
        }
        __syncthreads();   // B_lds dead; reuse region for h

        float vmax[4] = {-INFINITY, -INFINITY, -INFINITY, -INFINITY};
        const float* pcb = lpc + (size_t)b*1024*3;

        for (int p = 0; p < 4; ++p) {
            { // h for point p*256 + t -> lds[t][k] bf16 swizzled
                const float* pp = pcb + (p*256 + t)*3;
                float x = pp[0], y = pp[1], z = pp[2];
#pragma unroll
                for (int q = 0; q < 8; ++q) {
                    float hv[8];
#pragma unroll
                    for (int i = 0; i < 8; ++i) {
                        int k = q*8 + i;
                        hv[i] = lrelu(fmaf(x, lw1[k], fmaf(y, lw1[64+k], fmaf(z, lw1[128+k], lb1[k]))));
                    }
                    uint4 u = make_uint4(pack2(hv[0],hv[1]), pack2(hv[2],hv[3]),
                                         pack2(hv[4],hv[5]), pack2(hv[6],hv[7]));
                    *(uint4*)(lds + t*128 + ((q ^ (t & 7)) * 16)) = u;
                }
            }
            __syncthreads();
#pragma unroll 4
            for (int g = 0; g < 16; ++g) {
                int row = g*16 + (l & 15);
                bf16x8 A0 = *(const bf16x8*)(lds + row*128 + ((((l>>4))     ^ (row & 7)) * 16));
                bf16x8 A1 = *(const bf16x8*)(lds + row*128 + (((4 + (l>>4)) ^ (row & 7)) * 16));
#pragma unroll
                for (int c4 = 0; c4 < 4; ++c4) {
                    f32x4 acc = {0.f, 0.f, 0.f, 0.f};
                    acc = __builtin_amdgcn_mfma_f32_16x16x32_bf16(A0, Bf[c4][0], acc, 0, 0, 0);
                    acc = __builtin_amdgcn_mfma_f32_16x16x32_bf16(A1, Bf[c4][1], acc, 0, 0, 0);
                    vmax[c4] = fmaxf(vmax[c4],
                               fmaxf(fmaxf(acc[0], acc[1]), fmaxf(acc[2], acc[3])));
                }
            }
            __syncthreads();
        }
#pragma unroll
        for (int c4 = 0; c4 < 4; ++c4) {
            vmax[c4] = fmaxf(vmax[c4], __shfl_xor(vmax[c4], 16, 64));
            vmax[c4] = fmaxf(vmax[c4], __shfl_xor(vmax[c4], 32, 64));
        }
        if (l < 16) {
#pragma unroll
            for (int c4 = 0; c4 < 4; ++c4) {
                int c = w*64 + c4*16 + l;
                featb[(size_t)b*4608 + 2048 + c] = f2bf(lrelu(vmax[c4] + lb2[c]));
            }
        }
    } else {
        // ================= KNN + ATTENTION =================
        int b = blk - 384;
        float* knn_pos = (float*)smem;                  // [16][4]
        int*   knn_idx = (int*)(smem + 256);            // [16]
        float* sdw     = (float*)(smem + 320);          // [2][4]
        int*   siw     = (int*)(smem + 352);            // [2][4]
        float* h_all   = (float*)(smem + 384);          // [16][64]
        float* hqs     = (float*)(smem + 384 + 4096);   // [16][128]
        float* sc      = (float*)(smem + 384 + 12288);  // [16][128]

        int wv = t >> 6, l = t & 63;
        const float* pb = gpc + (size_t)b*4096*3;
        float qx = query[b*3+0], qy = query[b*3+1], qz = query[b*3+2];
        float sq = qx*qx + qy*qy + qz*qz;

        float d2[16];
#pragma unroll
        for (int j = 0; j < 16; ++j) {
            int n = t + 256*j;
            float px = pb[n*3+0], py = pb[n*3+1], pz = pb[n*3+2];
            float sp = px*px + py*py + pz*pz;
            d2[j] = sq + sp - 2.0f*(qx*px + qy*py + qz*pz);
        }
        int used = 0;
        for (int r = 0; r < 16; ++r) {
            float bd = INFINITY; int bi = 0x7fffffff;
#pragma unroll
            for (int j = 0; j < 16; ++j) {
                float d = (used & (1 << j)) ? INFINITY : d2[j];
                int n = t + 256*j;
                if (d < bd || (d == bd && n < bi)) { bd = d; bi = n; }
            }
#pragma unroll
            for (int off = 32; off; off >>= 1) {
                float od = __shfl_xor(bd, off, 64);
                int   oi = __shfl_xor(bi, off, 64);
                if (od < bd || (od == bd && oi < bi)) { bd = od; bi = oi; }
            }
            if (l == 0) { sdw[(r & 1)*4 + wv] = bd; siw[(r & 1)*4 + wv] = bi; }
            __syncthreads();
            float fd = sdw[(r & 1)*4]; int fi = siw[(r & 1)*4];
#pragma unroll
            for (int ww = 1; ww < 4; ++ww) {
                float od = sdw[(r & 1)*4 + ww]; int oi = siw[(r & 1)*4 + ww];
                if (od < fd || (od == fd && oi < fi)) { fd = od; fi = oi; }
            }
            if (t == 0) knn_idx[r] = fi;
            if ((fi & 255) == t) used |= 1 << (fi >> 8);
        }
        __syncthreads();
        if (t < 16) {
            int n = knn_idx[t];
            knn_pos[t*4+0] = qx - pb[n*3+0];
            knn_pos[t*4+1] = qy - pb[n*3+1];
            knn_pos[t*4+2] = qz - pb[n*3+2];
        }
        __syncthreads();
        { // h for 16 neighbors: thread (r = t>>4, 4 channels)
            int r = t >> 4, kk = (t & 15) * 4;
            float ppx = qx - knn_pos[r*4+0];
            float ppy = qy - knn_pos[r*4+1];
            float ppz = qz - knn_pos[r*4+2];
            float4 hv;
            float* h4 = (float*)&hv;
#pragma unroll
            for (int i = 0; i < 4; ++i) {
                int k = kk + i;
                h4[i] = lrelu(fmaf(ppx, gw1[k], fmaf(ppy, gw1[64+k], fmaf(ppz, gw1[128+k], gb1[k]))));
            }
            *(float4*)(h_all + r*64 + kk) = hv;
        }
        __syncthreads();
        { // hq[r][c] = lrelu(h@gw2 + gb2) + (knn_pos@apw + apb)
            int r = t >> 4, c0 = (t & 15) * 8;
            float acc[8];
#pragma unroll
            for (int i = 0; i < 8; ++i) acc[i] = gb2[c0+i];
            for (int k = 0; k < 64; ++k) {
                float hv = h_all[r*64 + k];
                float4 wv0 = *(const float4*)(gw2 + k*128 + c0);
                float4 wv1 = *(const float4*)(gw2 + k*128 + c0 + 4);
                acc[0] = fmaf(hv, wv0.x, acc[0]); acc[1] = fmaf(hv, wv0.y, acc[1]);
                acc[2] = fmaf(hv, wv0.z, acc[2]); acc[3] = fmaf(hv, wv0.w, acc[3]);
                acc[4] = fmaf(hv, wv1.x, acc[4]); acc[5] = fmaf(hv, wv1.y, acc[5]);
                acc[6] = fmaf(hv, wv1.z, acc[6]); acc[7] = fmaf(hv, wv1.w, acc[7]);
            }
            float kx = knn_pos[r*4+0], ky = knn_pos[r*4+1], kz = knn_pos[r*4+2];
#pragma unroll
            for (int i = 0; i < 8; ++i) {
                int c = c0 + i;
                float pe = fmaf(kx, apw[c], fmaf(ky, apw[128+c], fmaf(kz, apw[256+c], apb[c])));
                acc[i] = lrelu(acc[i]) + pe;
            }
            *(float4*)(hqs + r*128 + c0)     = make_float4(acc[0], acc[1], acc[2], acc[3]);
            *(float4*)(hqs + r*128 + c0 + 4) = make_float4(acc[4], acc[5], acc[6], acc[7]);
        }
        __syncthreads();
        { // scores sc[r][c] = hq @ asw + asb
            int r = t >> 4, c0 = (t & 15) * 8;
            float acc[8];
#pragma unroll
            for (int i = 0; i < 8; ++i) acc[i] = asb[c0+i];
            for (int k = 0; k < 128; ++k) {
                float hv = hqs[r*128 + k];
                float4 wv0 = *(const float4*)(asw + k*128 + c0);
                float4 wv1 = *(const float4*)(asw + k*128 + c0 + 4);
                acc[0] = fmaf(hv, wv0.x, acc[0]); acc[1] = fmaf(hv, wv0.y, acc[1]);
                acc[2] = fmaf(hv, wv0.z, acc[2]); acc[3] = fmaf(hv, wv0.w, acc[3]);
                acc[4] = fmaf(hv, wv1.x, acc[4]); acc[5] = fmaf(hv, wv1.y, acc[5]);
                acc[6] = fmaf(hv, wv1.z, acc[6]); acc[7] = fmaf(hv, wv1.w, acc[7]);
            }
            *(float4*)(sc + r*128 + c0)     = make_float4(acc[0], acc[1], acc[2], acc[3]);
            *(float4*)(sc + r*128 + c0 + 4) = make_float4(acc[4], acc[5], acc[6], acc[7]);
        }
        __syncthreads();
        if (t < 128) {
            int c = t;
            float s[16]; float mx = -INFINITY;
#pragma unroll
            for (int r = 0; r < 16; ++r) { s[r] = sc[r*128 + c]; mx = fmaxf(mx, s[r]); }
            float sum = 0.f;
#pragma unroll
            for (int r = 0; r < 16; ++r) { s[r] = expf(s[r] - mx); sum += s[r]; }
            float inv = 1.0f / sum;
            float qf = 0.f;
#pragma unroll
            for (int r = 0; r < 16; ++r) qf = fmaf(s[r]*inv, hqs[r*128 + c], qf);
            featb[(size_t)b*4608 + 2304 + c] = f2bf(qf);
            float pv = fmaf(qx, posw[c], fmaf(qy, posw[128+c], fmaf(qz, posw[256+c], posb[c])));
            pv = lrelu(fmaf(bng[c], pv, bnb[c]));
            featb[(size_t)b*4608 + 2432 + c] = f2bf(pv);
        }
    }
}

// ---------------------------------------------------------------------------
// Decoder layer 1, bf16 MFMA: [128,4608]bf16 @ [4608,512]f32->bf16.
// grid 256 = 4 Mgroups(32) x 8 Ngroups(64) x 8 Kchunks(576). 4 waves/block,
// each wave: 2 output tiles 16x16, K accumulated over 18 k-steps of 32.
// ---------------------------------------------------------------------------
__global__ __launch_bounds__(256) void k_dec1(
    const unsigned short* __restrict__ featb, const float* __restrict__ w1f,
    float* __restrict__ partial)      // [8][128][512]
{
    __shared__ __align__(16) unsigned char smem[4096 + 8192 + 16384];
    unsigned char* A_lds = smem;                         // [32][128B] swizzled
    unsigned char* B_lds = smem + 4096;                  // [64][128B] swizzled
    float* scr = (float*)(smem + 4096 + 8192);           // [64][64] f32

    int blk = blockIdx.x;
    int kc = blk & 7, ng = (blk >> 3) & 7, mg = blk >> 6;
    int m0 = mg*32, n0 = ng*64, kbase = kc*576;
    int t = threadIdx.x, w = t >> 6, l = t & 63;
    int mt = w >> 1, nt0 = (w & 1) * 2;

    f32x4 acc0 = {0.f,0.f,0.f,0.f}, acc1 = {0.f,0.f,0.f,0.f};

    for (int ss = 0; ss < 9; ++ss) {
        int k0 = kbase + ss*64;
        { // A stage: feat_bf[m0..m0+32][k0..k0+64] -> A_lds swizzled
            int row = t >> 3, ch = t & 7;
            uint4 av = *(const uint4*)((const unsigned char*)featb
                         + ((size_t)(m0 + row)*4608 + k0 + ch*8) * 2);
            *(uint4*)(A_lds + row*128 + ((ch ^ (row & 7)) * 16)) = av;
        }
        // B global f32 -> scratch
        for (int u = t; u < 1024; u += 256) {
            int row = u >> 4, c4 = u & 15;
            *(float4*)(scr + row*64 + c4*4) =
                *(const float4*)(w1f + (size_t)(k0 + row)*512 + n0 + c4*4);
        }
        __syncthreads();
        { // scratch -> B_lds[n][k] bf16 transposed + swizzled
            int n = t & 63, kh = t >> 6;
            float v[16];
#pragma unroll
            for (int i = 0; i < 16; ++i) v[i] = scr[(kh*16 + i)*64 + n];
            uint4 u0 = make_uint4(pack2(v[0],v[1]),  pack2(v[2],v[3]),
                                  pack2(v[4],v[5]),  pack2(v[6],v[7]));
            uint4 u1 = make_uint4(pack2(v[8],v[9]),  pack2(v[10],v[11]),
                                  pack2(v[12],v[13]),pack2(v[14],v[15]));
            *(uint4*)(B_lds + n*128 + (((kh*2)     ^ (n & 7)) * 16)) = u0;
            *(uint4*)(B_lds + n*128 + (((kh*2 + 1) ^ (n & 7)) * 16)) = u1;
        }
        __syncthreads();
        {
            int am = mt*16 + (l & 15);
            int bn0 = nt0*16 + (l & 15), bn1 = (nt0 + 1)*16 + (l & 15);
#pragma unroll
            for (int ks = 0; ks < 2; ++ks) {
                int chunk = ks*4 + (l >> 4);
                bf16x8 Af = *(const bf16x8*)(A_lds + am*128 + ((chunk ^ (am & 7)) * 16));
                bf16x8 B0 = *(const bf16x8*)(B_lds + bn0*128 + ((chunk ^ (bn0 & 7)) * 16));
                bf16x8 B1 = *(const bf16x8*)(B_lds + bn1*128 + ((chunk ^ (bn1 & 7)) * 16));
                acc0 = __builtin_amdgcn_mfma_f32_16x16x32_bf16(Af, B0, acc0, 0, 0, 0);
                acc1 = __builtin_amdgcn_mfma_f32_16x16x32_bf16(Af, B1, acc1, 0, 0, 0);
            }
        }
        __syncthreads();
    }
    int col0 = n0 + nt0*16 + (l & 15);
    int col1 = n0 + (nt0 + 1)*16 + (l & 15);
#pragma unroll
    for (int r = 0; r < 4; ++r) {
        int row = m0 + mt*16 + (l >> 4)*4 + r;
        partial[((size_t)kc*128 + row)*512 + col0] = acc0[r];
        partial[((size_t)kc*128 + row)*512 + col1] = acc1[r];
    }
}

// ---------------------------------------------------------------------------
// Decoder tail: sum K-chunk partials, +b1, lrelu, dot dec_w2, +b2.
// ---------------------------------------------------------------------------
__global__ __launch_bounds__(512) void k_dec2(
    const float* __restrict__ partial, const float* __restrict__ b1,
    const float* __restrict__ w2, const float* __restrict__ b2,
    float* __restrict__ out)
{
    int b = blockIdx.x, t = threadIdx.x;
    float acc = b1[t];
#pragma unroll
    for (int kc = 0; kc < 8; ++kc)
        acc += partial[((size_t)kc*128 + b)*512 + t];
    float v = lrelu(acc) * w2[t];
#pragma unroll
    for (int off = 32; off; off >>= 1) v += __shfl_xor(v, off, 64);
    __shared__ float red[8];
    if ((t & 63) == 0) red[t >> 6] = v;
    __syncthreads();
    if (t == 0) {
        float s_ = 0.f;
#pragma unroll
        for (int i = 0; i < 8; ++i) s_ += red[i];
        out[b] = s_ + b2[0];
    }
}

extern "C" void kernel_launch(void* const* d_in, const int* in_sizes, int n_in,
                              void* d_out, int out_size, void* d_ws, size_t ws_size,
                              hipStream_t stream)
{
    const float* pc_voxel  = (const float*)d_in[0];
    const float* global_pc = (const float*)d_in[1];
    const float* local_pc  = (const float*)d_in[2];
    const float* query     = (const float*)d_in[3];
    const float* voxel     = (const float*)d_in[4];
    const float* ge_w1 = (const float*)d_in[5];
    const float* ge_b1 = (const float*)d_in[6];
    const float* ge_w2 = (const float*)d_in[7];
    const float* ge_b2 = (const float*)d_in[8];
    // d_in[9..10] = ge_w3/ge_b3: dead (global_c unused by decoder)
    const float* le_w1 = (const float*)d_in[11];
    const float* le_b1 = (const float*)d_in[12];
    const float* le_w2 = (const float*)d_in[13];
    const float* le_b2 = (const float*)d_in[14];
    const float* pos_w = (const float*)d_in[15];
    const float* pos_b = (const float*)d_in[16];
    const float* bn_g  = (const float*)d_in[17];
    const float* bn_b  = (const float*)d_in[18];
    const float* apw   = (const float*)d_in[19];
    const float* apb   = (const float*)d_in[20];
    const float* asw   = (const float*)d_in[21];
    const float* asb   = (const float*)d_in[22];
    const float* gw1 = (const float*)d_in[23];
    const float* gb1 = (const float*)d_in[24];
    const float* gw2 = (const float*)d_in[25];
    const float* gb2 = (const float*)d_in[26];
    const float* fw1 = (const float*)d_in[27];
    const float* fb1 = (const float*)d_in[28];
    const float* fw2 = (const float*)d_in[29];
    const float* fb2 = (const float*)d_in[30];
    const float* dw1 = (const float*)d_in[31];
    const float* db1 = (const float*)d_in[32];
    const float* dw2 = (const float*)d_in[33];
    const float* db2 = (const float*)d_in[34];

    unsigned short* featb = (unsigned short*)d_ws;           // 128*4608 bf16 = 1.18MB
    float* partial = (float*)((char*)d_ws + 1179648);        // 8*128*512 f32 = 2MB
    float* out = (float*)d_out;

    k_fused<<<512, 256, 0, stream>>>(
        pc_voxel, voxel, gw1, gb1, gw2, gb2, fw1, fb1, fw2, fb2,
        local_pc, le_w1, le_b1, le_w2, le_b2,
        global_pc, query, ge_w1, ge_b1, ge_w2, ge_b2,
        apw, apb, asw, asb, pos_w, pos_b, bn_g, bn_b,
        featb);
    k_dec1<<<256, 256, 0, stream>>>(featb, dw1, partial);
    k_dec2<<<128, 512, 0, stream>>>(partial, db1, dw2, db2, out);
}

// Round 3
// 195.505 us; speedup vs baseline: 2.0132x; 1.3388x over previous
//
#include <hip/hip_runtime.h>
#include <math.h>

#define LEAKY 0.2f
__device__ __forceinline__ float lrelu(float x){ return x >= 0.0f ? x : LEAKY*x; }

__device__ __forceinline__ unsigned short f2bf(float x){
    union { float f; unsigned u; } v; v.f = x;
    unsigned r = v.u + 0x7FFFu + ((v.u >> 16) & 1u);
    return (unsigned short)(r >> 16);
}
__device__ __forceinline__ unsigned pack2(float a, float b){
    return (unsigned)f2bf(a) | ((unsigned)f2bf(b) << 16);
}

typedef __attribute__((ext_vector_type(8))) short bf16x8;
typedef __attribute__((ext_vector_type(4))) float f32x4;

// ---------------------------------------------------------------------------
// Fused: blocks [0,256) voxel (MFMA conv), [256,384) local enc (MFMA),
// [384,512) KNN+attention. All write feat_bf[128][4608] bf16.
// smem 64 KB -> 2 blocks/CU.
// ---------------------------------------------------------------------------
__global__ __launch_bounds__(256) void k_fused(
    const float* __restrict__ pcv, const float* __restrict__ vox,
    const float* __restrict__ gvw1, const float* __restrict__ gvb1,
    const float* __restrict__ gvw2, const float* __restrict__ gvb2,
    const float* __restrict__ fvw1, const float* __restrict__ fvb1,
    const float* __restrict__ fvw2, const float* __restrict__ fvb2,
    const float* __restrict__ lpc,
    const float* __restrict__ lw1, const float* __restrict__ lb1,
    const float* __restrict__ lw2, const float* __restrict__ lb2,
    const float* __restrict__ gpc, const float* __restrict__ query,
    const float* __restrict__ gw1, const float* __restrict__ gb1,
    const float* __restrict__ gw2, const float* __restrict__ gb2,
    const float* __restrict__ apw, const float* __restrict__ apb,
    const float* __restrict__ asw, const float* __restrict__ asb,
    const float* __restrict__ posw, const float* __restrict__ posb,
    const float* __restrict__ bng, const float* __restrict__ bnb,
    unsigned short* __restrict__ featb)
{
    __shared__ __align__(16) unsigned char smem[65536];
    int blk = blockIdx.x;
    int t = threadIdx.x;
    int w = t >> 6, l = t & 63;

    if (blk < 256) {
        // ================= VOXEL (MFMA conv1+conv2) =================
        int branch = blk >> 7, b = blk & 127;
        const float* in = (branch ? vox : pcv) + (size_t)b*4096;
        const float* w1 = branch ? fvw1 : gvw1;
        const float* b1 = branch ? fvb1 : gvb1;
        const float* w2 = branch ? fvw2 : gvw2;
        const float* b2 = branch ? fvb2 : gvb2;

        float* s_in = (float*)smem;                         // [17][17][17] f32, 19652 B
        unsigned short* mid = (unsigned short*)smem;        // [9][9][9][16] bf16, 23328 B (after s_in dead)
        unsigned char* im2c = smem + 24576;                 // [512][80 B] bf16 rows (k 0..31 in first 64 B)

        // phase 1: zero pad-cube, fill
        for (int i = t; i < 4913; i += 256) s_in[i] = 0.f;
        __syncthreads();
        for (int i = t; i < 4096; i += 256) {
            int id = i >> 8, ih = (i >> 4) & 15, iw = i & 15;
            s_in[id*289 + ih*17 + iw] = in[i];
        }
        __syncthreads();

        // phase 2: im2col build (2 sp rows per thread)
#pragma unroll
        for (int half = 0; half < 2; ++half) {
            int sp = t + half*256;
            int od = sp >> 6, oh = (sp >> 3) & 7, ow = sp & 7;
            const float* base = s_in + (2*od)*289 + (2*oh)*17 + 2*ow;
            float e[27];
#pragma unroll
            for (int kd = 0; kd < 3; ++kd)
#pragma unroll
                for (int kh = 0; kh < 3; ++kh)
#pragma unroll
                    for (int kw = 0; kw < 3; ++kw)
                        e[(kd*3+kh)*3+kw] = base[kd*289 + kh*17 + kw];
            unsigned* row = (unsigned*)(im2c + sp*80);
#pragma unroll
            for (int kk = 0; kk < 13; ++kk) row[kk] = pack2(e[2*kk], e[2*kk+1]);
            row[13] = pack2(e[26], 0.f);
            row[14] = 0u; row[15] = 0u;
        }
        __syncthreads();

        // phase 3: zero mid (overlaps dead s_in)
        for (int i = t; i < 5832; i += 256) ((unsigned*)mid)[i] = 0u;
        __syncthreads();

        // phase 4: conv1 MFMA  [512 x 32k] @ [32k x 16co]
        {
            int co = l & 15, q = l >> 4;
            bf16x8 Bf;
#pragma unroll
            for (int j = 0; j < 8; ++j) {
                int k = q*8 + j;
                float wv = (k < 27) ? w1[k*16 + co] : 0.f;
                Bf[j] = (short)f2bf(wv);
            }
            float bias = b1[co];
#pragma unroll
            for (int mi8 = 0; mi8 < 8; ++mi8) {
                int mi = w*8 + mi8;
                int sp = mi*16 + (l & 15);
                bf16x8 Af = *(const bf16x8*)(im2c + sp*80 + q*16);
                f32x4 acc = {0.f,0.f,0.f,0.f};
                acc = __builtin_amdgcn_mfma_f32_16x16x32_bf16(Af, Bf, acc, 0, 0, 0);
#pragma unroll
                for (int r = 0; r < 4; ++r) {
                    int osp = mi*16 + q*4 + r;
                    int od = osp >> 6, oh = (osp >> 3) & 7, ow = osp & 7;
                    mid[(od*81 + oh*9 + ow)*16 + co] = f2bf(lrelu(acc[r] + bias));
                }
            }
        }
        __syncthreads();

        // phase 5: conv2 MFMA  [64 x 432k] @ [432k x 32co], kp-pairs (K=32/step)
        {
            int nw = w & 1, mbase = (w >> 1) * 2;
            int co = nw*16 + (l & 15);
            int q = l >> 4;
            int q2 = q >> 1, ci0 = (q & 1)*8;
            int sp0 = mbase*16 + (l & 15);
            int sp1 = sp0 + 16;
            int s0 = ((sp0 >> 4)*2)*81 + (((sp0 >> 2) & 3)*2)*9 + (sp0 & 3)*2;
            int s1 = ((sp1 >> 4)*2)*81 + (((sp1 >> 2) & 3)*2)*9 + (sp1 & 3)*2;
            f32x4 acc0 = {0.f,0.f,0.f,0.f}, acc1 = {0.f,0.f,0.f,0.f};
#pragma unroll
            for (int ks = 0; ks < 14; ++ks) {
                int kp = 2*ks + q2;
                bool ok = (kp < 27);
                int kpc = ok ? kp : 0;
                int kpoff = (kpc/9)*81 + ((kpc/3)%3)*9 + (kpc%3);
                bf16x8 A0 = *(const bf16x8*)(mid + (s0 + kpoff)*16 + ci0);
                bf16x8 A1 = *(const bf16x8*)(mid + (s1 + kpoff)*16 + ci0);
                bf16x8 Bf;
#pragma unroll
                for (int j = 0; j < 8; ++j) {
                    float wv = w2[(kpc*16 + ci0 + j)*32 + co];
                    Bf[j] = (short)f2bf(ok ? wv : 0.f);
                }
                if (!ok) { A0 = bf16x8{0,0,0,0,0,0,0,0}; A1 = bf16x8{0,0,0,0,0,0,0,0}; }
                acc0 = __builtin_amdgcn_mfma_f32_16x16x32_bf16(A0, Bf, acc0, 0, 0, 0);
                acc1 = __builtin_amdgcn_mfma_f32_16x16x32_bf16(A1, Bf, acc1, 0, 0, 0);
            }
            float bias = b2[co];
            unsigned short* o = featb + (size_t)b*4608 + (branch ? 2560 : 0);
#pragma unroll
            for (int r = 0; r < 4; ++r) {
                int spa = mbase*16 + q*4 + r;
                o[co*64 + spa]      = f2bf(lrelu(acc0[r] + bias));
                o[co*64 + spa + 16] = f2bf(lrelu(acc1[r] + bias));
            }
        }
    } else if (blk < 384) {
        // ================= LOCAL ENCODER (bf16 MFMA) =================
        int b = blk - 256;
        unsigned char* lds = smem;

#pragma unroll
        for (int q = 0; q < 8; ++q) {
            float f0 = lw2[(q*8+0)*256 + t], f1 = lw2[(q*8+1)*256 + t];
            float f2 = lw2[(q*8+2)*256 + t], f3 = lw2[(q*8+3)*256 + t];
            float f4 = lw2[(q*8+4)*256 + t], f5 = lw2[(q*8+5)*256 + t];
            float f6 = lw2[(q*8+6)*256 + t], f7 = lw2[(q*8+7)*256 + t];
            uint4 u = make_uint4(pack2(f0,f1), pack2(f2,f3), pack2(f4,f5), pack2(f6,f7));
            *(uint4*)(lds + t*128 + ((q ^ (t & 7)) * 16)) = u;
        }
        __syncthreads();

        bf16x8 Bf[4][2];
#pragma unroll
        for (int c4 = 0; c4 < 4; ++c4) {
#pragma unroll
            for (int ks = 0; ks < 2; ++ks) {
                int c = w*64 + c4*16 + (l & 15);
                int chunk = ks*4 + (l >> 4);
                Bf[c4][ks] = *(const bf16x8*)(lds + c*128 + ((chunk ^ (c & 7)) * 16));
            }
        }
        __syncthreads();

        float vmax[4] = {-INFINITY, -INFINITY, -INFINITY, -INFINITY};
        const float* pcb = lpc + (size_t)b*1024*3;

        for (int p = 0; p < 4; ++p) {
            {
                const float* pp = pcb + (p*256 + t)*3;
                float x = pp[0], y = pp[1], z = pp[2];
#pragma unroll
                for (int q = 0; q < 8; ++q) {
                    float hv[8];
#pragma unroll
                    for (int i = 0; i < 8; ++i) {
                        int k = q*8 + i;
                        hv[i] = lrelu(fmaf(x, lw1[k], fmaf(y, lw1[64+k], fmaf(z, lw1[128+k], lb1[k]))));
                    }
                    uint4 u = make_uint4(pack2(hv[0],hv[1]), pack2(hv[2],hv[3]),
                                         pack2(hv[4],hv[5]), pack2(hv[6],hv[7]));
                    *(uint4*)(lds + t*128 + ((q ^ (t & 7)) * 16)) = u;
                }
            }
            __syncthreads();
#pragma unroll 4
            for (int g = 0; g < 16; ++g) {
                int row = g*16 + (l & 15);
                bf16x8 A0 = *(const bf16x8*)(lds + row*128 + ((((l>>4))     ^ (row & 7)) * 16));
                bf16x8 A1 = *(const bf16x8*)(lds + row*128 + (((4 + (l>>4)) ^ (row & 7)) * 16));
#pragma unroll
                for (int c4 = 0; c4 < 4; ++c4) {
                    f32x4 acc = {0.f, 0.f, 0.f, 0.f};
                    acc = __builtin_amdgcn_mfma_f32_16x16x32_bf16(A0, Bf[c4][0], acc, 0, 0, 0);
                    acc = __builtin_amdgcn_mfma_f32_16x16x32_bf16(A1, Bf[c4][1], acc, 0, 0, 0);
                    vmax[c4] = fmaxf(vmax[c4],
                               fmaxf(fmaxf(acc[0], acc[1]), fmaxf(acc[2], acc[3])));
                }
            }
            __syncthreads();
        }
#pragma unroll
        for (int c4 = 0; c4 < 4; ++c4) {
            vmax[c4] = fmaxf(vmax[c4], __shfl_xor(vmax[c4], 16, 64));
            vmax[c4] = fmaxf(vmax[c4], __shfl_xor(vmax[c4], 32, 64));
        }
        if (l < 16) {
#pragma unroll
            for (int c4 = 0; c4 < 4; ++c4) {
                int c = w*64 + c4*16 + l;
                featb[(size_t)b*4608 + 2048 + c] = f2bf(lrelu(vmax[c4] + lb2[c]));
            }
        }
    } else {
        // ================= KNN + ATTENTION =================
        int b = blk - 384;
        float* knn_pos = (float*)smem;
        int*   knn_idx = (int*)(smem + 256);
        float* sdw     = (float*)(smem + 320);
        int*   siw     = (int*)(smem + 352);
        float* h_all   = (float*)(smem + 384);
        float* hqs     = (float*)(smem + 384 + 4096);
        float* sc      = (float*)(smem + 384 + 12288);

        int wv = w;
        const float* pb = gpc + (size_t)b*4096*3;
        float qx = query[b*3+0], qy = query[b*3+1], qz = query[b*3+2];
        float sq = qx*qx + qy*qy + qz*qz;

        float d2[16];
#pragma unroll
        for (int j = 0; j < 16; ++j) {
            int n = t + 256*j;
            float px = pb[n*3+0], py = pb[n*3+1], pz = pb[n*3+2];
            float sp = px*px + py*py + pz*pz;
            d2[j] = sq + sp - 2.0f*(qx*px + qy*py + qz*pz);
        }
        int used = 0;
        for (int r = 0; r < 16; ++r) {
            float bd = INFINITY; int bi = 0x7fffffff;
#pragma unroll
            for (int j = 0; j < 16; ++j) {
                float d = (used & (1 << j)) ? INFINITY : d2[j];
                int n = t + 256*j;
                if (d < bd || (d == bd && n < bi)) { bd = d; bi = n; }
            }
#pragma unroll
            for (int off = 32; off; off >>= 1) {
                float od = __shfl_xor(bd, off, 64);
                int   oi = __shfl_xor(bi, off, 64);
                if (od < bd || (od == bd && oi < bi)) { bd = od; bi = oi; }
            }
            if (l == 0) { sdw[(r & 1)*4 + wv] = bd; siw[(r & 1)*4 + wv] = bi; }
            __syncthreads();
            float fd = sdw[(r & 1)*4]; int fi = siw[(r & 1)*4];
#pragma unroll
            for (int ww = 1; ww < 4; ++ww) {
                float od = sdw[(r & 1)*4 + ww]; int oi = siw[(r & 1)*4 + ww];
                if (od < fd || (od == fd && oi < fi)) { fd = od; fi = oi; }
            }
            if (t == 0) knn_idx[r] = fi;
            if ((fi & 255) == t) used |= 1 << (fi >> 8);
        }
        __syncthreads();
        if (t < 16) {
            int n = knn_idx[t];
            knn_pos[t*4+0] = qx - pb[n*3+0];
            knn_pos[t*4+1] = qy - pb[n*3+1];
            knn_pos[t*4+2] = qz - pb[n*3+2];
        }
        __syncthreads();
        {
            int r = t >> 4, kk = (t & 15) * 4;
            float ppx = qx - knn_pos[r*4+0];
            float ppy = qy - knn_pos[r*4+1];
            float ppz = qz - knn_pos[r*4+2];
            float4 hv;
            float* h4 = (float*)&hv;
#pragma unroll
            for (int i = 0; i < 4; ++i) {
                int k = kk + i;
                h4[i] = lrelu(fmaf(ppx, gw1[k], fmaf(ppy, gw1[64+k], fmaf(ppz, gw1[128+k], gb1[k]))));
            }
            *(float4*)(h_all + r*64 + kk) = hv;
        }
        __syncthreads();
        {
            int r = t >> 4, c0 = (t & 15) * 8;
            float acc[8];
#pragma unroll
            for (int i = 0; i < 8; ++i) acc[i] = gb2[c0+i];
            for (int k = 0; k < 64; ++k) {
                float hv = h_all[r*64 + k];
                float4 wv0 = *(const float4*)(gw2 + k*128 + c0);
                float4 wv1 = *(const float4*)(gw2 + k*128 + c0 + 4);
                acc[0] = fmaf(hv, wv0.x, acc[0]); acc[1] = fmaf(hv, wv0.y, acc[1]);
                acc[2] = fmaf(hv, wv0.z, acc[2]); acc[3] = fmaf(hv, wv0.w, acc[3]);
                acc[4] = fmaf(hv, wv1.x, acc[4]); acc[5] = fmaf(hv, wv1.y, acc[5]);
                acc[6] = fmaf(hv, wv1.z, acc[6]); acc[7] = fmaf(hv, wv1.w, acc[7]);
            }
            float kx = knn_pos[r*4+0], ky = knn_pos[r*4+1], kz = knn_pos[r*4+2];
#pragma unroll
            for (int i = 0; i < 8; ++i) {
                int c = c0 + i;
                float pe = fmaf(kx, apw[c], fmaf(ky, apw[128+c], fmaf(kz, apw[256+c], apb[c])));
                acc[i] = lrelu(acc[i]) + pe;
            }
            *(float4*)(hqs + r*128 + c0)     = make_float4(acc[0], acc[1], acc[2], acc[3]);
            *(float4*)(hqs + r*128 + c0 + 4) = make_float4(acc[4], acc[5], acc[6], acc[7]);
        }
        __syncthreads();
        {
            int r = t >> 4, c0 = (t & 15) * 8;
            float acc[8];
#pragma unroll
            for (int i = 0; i < 8; ++i) acc[i] = asb[c0+i];
            for (int k = 0; k < 128; ++k) {
                float hv = hqs[r*128 + k];
                float4 wv0 = *(const float4*)(asw + k*128 + c0);
                float4 wv1 = *(const float4*)(asw + k*128 + c0 + 4);
                acc[0] = fmaf(hv, wv0.x, acc[0]); acc[1] = fmaf(hv, wv0.y, acc[1]);
                acc[2] = fmaf(hv, wv0.z, acc[2]); acc[3] = fmaf(hv, wv0.w, acc[3]);
                acc[4] = fmaf(hv, wv1.x, acc[4]); acc[5] = fmaf(hv, wv1.y, acc[5]);
                acc[6] = fmaf(hv, wv1.z, acc[6]); acc[7] = fmaf(hv, wv1.w, acc[7]);
            }
            *(float4*)(sc + r*128 + c0)     = make_float4(acc[0], acc[1], acc[2], acc[3]);
            *(float4*)(sc + r*128 + c0 + 4) = make_float4(acc[4], acc[5], acc[6], acc[7]);
        }
        __syncthreads();
        if (t < 128) {
            int c = t;
            float s[16]; float mx = -INFINITY;
#pragma unroll
            for (int r = 0; r < 16; ++r) { s[r] = sc[r*128 + c]; mx = fmaxf(mx, s[r]); }
            float sum = 0.f;
#pragma unroll
            for (int r = 0; r < 16; ++r) { s[r] = expf(s[r] - mx); sum += s[r]; }
            float inv = 1.0f / sum;
            float qf = 0.f;
#pragma unroll
            for (int r = 0; r < 16; ++r) qf = fmaf(s[r]*inv, hqs[r*128 + c], qf);
            featb[(size_t)b*4608 + 2304 + c] = f2bf(qf);
            float pv = fmaf(qx, posw[c], fmaf(qy, posw[128+c], fmaf(qz, posw[256+c], posb[c])));
            pv = lrelu(fmaf(bng[c], pv, bnb[c]));
            featb[(size_t)b*4608 + 2432 + c] = f2bf(pv);
        }
    }
}

// ---------------------------------------------------------------------------
// Decoder layer 1: LDS-free register MFMA GEMM [128,4608]bf16 @ [4608,512].
// grid (36 kc, 2 mg, 8 ng), 4 waves = 4 n-tiles. Fragments loaded directly
// from global in fragment order (B coalesced 64B/16 lanes, A 16B/lane).
// ---------------------------------------------------------------------------
__global__ __launch_bounds__(256) void k_dec1(
    const unsigned short* __restrict__ featb, const float* __restrict__ w1f,
    float* __restrict__ partial)      // [36][128][512]
{
    int kc = blockIdx.x, mg = blockIdx.y, ng = blockIdx.z;
    int t = threadIdx.x, w = t >> 6, l = t & 63;
    int q = l >> 4;
    int n0 = ng*64 + w*16 + (l & 15);

    f32x4 acc[4] = {{0.f,0.f,0.f,0.f},{0.f,0.f,0.f,0.f},
                    {0.f,0.f,0.f,0.f},{0.f,0.f,0.f,0.f}};
#pragma unroll
    for (int ks = 0; ks < 4; ++ks) {
        int ka = (kc*4 + ks)*32 + q*8;
        bf16x8 Bf;
#pragma unroll
        for (int j = 0; j < 8; ++j) {
            float wv = w1f[(size_t)(ka + j)*512 + n0];
            Bf[j] = (short)f2bf(wv);
        }
#pragma unroll
        for (int mi = 0; mi < 4; ++mi) {
            int row = (mg*4 + mi)*16 + (l & 15);
            bf16x8 Af = *(const bf16x8*)(featb + (size_t)row*4608 + ka);
            acc[mi] = __builtin_amdgcn_mfma_f32_16x16x32_bf16(Af, Bf, acc[mi], 0, 0, 0);
        }
    }
    float* pb = partial + (size_t)kc*65536;
#pragma unroll
    for (int mi = 0; mi < 4; ++mi) {
#pragma unroll
        for (int r = 0; r < 4; ++r) {
            int row = (mg*4 + mi)*16 + q*4 + r;
            pb[row*512 + n0] = acc[mi][r];
        }
    }
}

// ---------------------------------------------------------------------------
// Decoder tail: sum 36 K-chunk partials, +b1, lrelu, dot dec_w2, +b2.
// ---------------------------------------------------------------------------
__global__ __launch_bounds__(512) void k_dec2(
    const float* __restrict__ partial, const float* __restrict__ b1,
    const float* __restrict__ w2, const float* __restrict__ b2,
    float* __restrict__ out)
{
    int b = blockIdx.x, t = threadIdx.x;
    float acc = b1[t];
    for (int kc = 0; kc < 36; ++kc)
        acc += partial[(size_t)kc*65536 + b*512 + t];
    float v = lrelu(acc) * w2[t];
#pragma unroll
    for (int off = 32; off; off >>= 1) v += __shfl_xor(v, off, 64);
    __shared__ float red[8];
    if ((t & 63) == 0) red[t >> 6] = v;
    __syncthreads();
    if (t == 0) {
        float s_ = 0.f;
#pragma unroll
        for (int i = 0; i < 8; ++i) s_ += red[i];
        out[b] = s_ + b2[0];
    }
}

extern "C" void kernel_launch(void* const* d_in, const int* in_sizes, int n_in,
                              void* d_out, int out_size, void* d_ws, size_t ws_size,
                              hipStream_t stream)
{
    const float* pc_voxel  = (const float*)d_in[0];
    const float* global_pc = (const float*)d_in[1];
    const float* local_pc  = (const float*)d_in[2];
    const float* query     = (const float*)d_in[3];
    const float* voxel     = (const float*)d_in[4];
    const float* ge_w1 = (const float*)d_in[5];
    const float* ge_b1 = (const float*)d_in[6];
    const float* ge_w2 = (const float*)d_in[7];
    const float* ge_b2 = (const float*)d_in[8];
    // d_in[9..10] = ge_w3/ge_b3: dead (global_c unused by decoder)
    const float* le_w1 = (const float*)d_in[11];
    const float* le_b1 = (const float*)d_in[12];
    const float* le_w2 = (const float*)d_in[13];
    const float* le_b2 = (const float*)d_in[14];
    const float* pos_w = (const float*)d_in[15];
    const float* pos_b = (const float*)d_in[16];
    const float* bn_g  = (const float*)d_in[17];
    const float* bn_b  = (const float*)d_in[18];
    const float* apw   = (const float*)d_in[19];
    const float* apb   = (const float*)d_in[20];
    const float* asw   = (const float*)d_in[21];
    const float* asb   = (const float*)d_in[22];
    const float* gw1 = (const float*)d_in[23];
    const float* gb1 = (const float*)d_in[24];
    const float* gw2 = (const float*)d_in[25];
    const float* gb2 = (const float*)d_in[26];
    const float* fw1 = (const float*)d_in[27];
    const float* fb1 = (const float*)d_in[28];
    const float* fw2 = (const float*)d_in[29];
    const float* fb2 = (const float*)d_in[30];
    const float* dw1 = (const float*)d_in[31];
    const float* db1 = (const float*)d_in[32];
    const float* dw2 = (const float*)d_in[33];
    const float* db2 = (const float*)d_in[34];

    unsigned short* featb = (unsigned short*)d_ws;        // 128*4608*2 = 1179648 B
    float* partial = (float*)((char*)d_ws + 1179648);     // 36*128*512*4 = 9437184 B
    float* out = (float*)d_out;

    k_fused<<<512, 256, 0, stream>>>(
        pc_voxel, voxel, gw1, gb1, gw2, gb2, fw1, fb1, fw2, fb2,
        local_pc, le_w1, le_b1, le_w2, le_b2,
        global_pc, query, ge_w1, ge_b1, ge_w2, ge_b2,
        apw, apb, asw, asb, pos_w, pos_b, bn_g, bn_b,
        featb);
    k_dec1<<<dim3(36, 2, 8), 256, 0, stream>>>(featb, dw1, partial);
    k_dec2<<<128, 512, 0, stream>>>(partial, db1, dw2, db2, out);
}